// Round 5
// baseline (548.961 us; speedup 1.0000x reference)
//
#include <hip/hip_runtime.h>

typedef __attribute__((ext_vector_type(8))) short bf16x8;
typedef __attribute__((ext_vector_type(4))) float f32x4;

// ---------------- problem constants ----------------
constexpr int B_   = 32;
constexpr int CIN  = 256;
constexpr int HW   = 56 * 56;      // 3136
constexpr int BOT  = 128;
constexpr int GRW  = 32;
constexpr int COUT = CIN + GRW;    // 288
constexpr int NBATCH = B_ * CIN * HW;   // 25,690,112
constexpr int NX2    = B_ * BOT * HW;   // 12,845,056
constexpr int NX3    = B_ * GRW * HW;   // 3,211,264
constexpr int NOUT   = B_ * COUT * HW;  // 28,901,376

// ---------------- workspace layout ----------------
// scal u32: [0]=max_x1 [1]=max|batch| [2]=max_x2 [3]=max|x3|
constexpr int OFF_W1Q  = 16;
constexpr int OFF_B1Q  = OFF_W1Q + 256;          // 272
constexpr int OFF_BFQ  = OFF_B1Q + 256;          // 528
constexpr int OFF_SC1  = OFF_BFQ + 128;          // 656
constexpr int OFF_SC2  = OFF_SC1 + 128;          // 784
constexpr int OFF_WQ1B = OFF_SC2 + 32;           // 816  ushort[128*256]
constexpr int OFF_W2B  = OFF_WQ1B + 16384;       // 17200 ushort[9*32*128]
constexpr int OFF_END  = OFF_W2B + 18432;        // 35632 floats
constexpr size_t X1B_BYTE = (size_t)OFF_END * 4;            // bf16-int x1 [b][hw][c] (51.4MB)
constexpr size_t X2_BYTE  = X1B_BYTE + (size_t)NBATCH * 2;  // fp32 x2 [b][o][hw]    (51.4MB)
constexpr size_t X2B_BYTE = X1B_BYTE;   // alias: bf16-int x2 [b][hw][c] (x1b dead after conv1)
constexpr size_t X3_BYTE  = X2_BYTE;    // alias: fp32 x3 [b][g][hw]     (x2 dead after quant2)

__device__ __forceinline__ float blockReduceMax256(float v) {
    #pragma unroll
    for (int o = 32; o > 0; o >>= 1) v = fmaxf(v, __shfl_down(v, o, 64));
    __shared__ float sm[4];
    if ((threadIdx.x & 63) == 0) sm[threadIdx.x >> 6] = v;
    __syncthreads();
    return fmaxf(fmaxf(sm[0], sm[1]), fmaxf(sm[2], sm[3]));
}
__device__ __forceinline__ float waveReduceMax(float v) {
    #pragma unroll
    for (int o = 32; o > 0; o >>= 1) v = fmaxf(v, __shfl_down(v, o, 64));
    return v;
}
__device__ __forceinline__ float clamp8(float r)   { return fminf(fmaxf(r, -128.0f), 127.0f); }
__device__ __forceinline__ float clampBig(float r) { return fminf(fmaxf(r, -2147483648.0f), 2147483648.0f); }
__device__ __forceinline__ unsigned short bf16u(float f) { return (unsigned short)(__float_as_uint(f) >> 16); }

// ---------------- prep1 ----------------
__global__ void prep1_kernel(const float* __restrict__ g1, const float* __restrict__ b1p,
                             const float* __restrict__ m1, const float* __restrict__ v1,
                             const float* __restrict__ s_in_p, float* __restrict__ ws) {
    int c = threadIdx.x;
    unsigned* scal = (unsigned*)ws;
    if (c < 16) scal[c] = 0u;
    float s_in = *s_in_p;
    float r = 1.0f / sqrtf(v1[c] + 1e-5f);
    float w1 = __fmul_rn(g1[c], r);
    float b1 = __fsub_rn(b1p[c], __fmul_rn(m1[c], w1));
    float mx = blockReduceMax256(fabsf(w1));
    float s_bn = mx / 127.0f + 1e-8f;
    ws[OFF_W1Q + c] = __fmul_rn(clamp8(rintf(w1 / s_bn)), s_bn);
    float sb = __fmul_rn(s_in, s_bn);
    ws[OFF_B1Q + c] = __fmul_rn(clampBig(rintf(b1 / sb)), sb);
}

// ---------------- max1: 8 independent loads/thread for MLP ----------------
__global__ __launch_bounds__(256) void max1_kernel(const float4* __restrict__ batch4,
                                                   float* __restrict__ ws) {
    const float* w1q = ws + OFF_W1Q;
    const float* b1q = ws + OFF_B1Q;
    int base = blockIdx.x * 2048 + threadIdx.x;   // grid 3136: 3136*2048 = NBATCH/4 exactly
    float4 v[8];
    #pragma unroll
    for (int j = 0; j < 8; j++) v[j] = batch4[base + j * 256];
    float mx1 = 0.0f, mxb = 0.0f;
    #pragma unroll
    for (int j = 0; j < 8; j++) {
        int i = base + j * 256;
        int c = (i / 784) & 255;
        float w = w1q[c], b = b1q[c];
        float x0 = fmaxf(__fadd_rn(__fmul_rn(v[j].x, w), b), 0.0f);
        float x1 = fmaxf(__fadd_rn(__fmul_rn(v[j].y, w), b), 0.0f);
        float x2 = fmaxf(__fadd_rn(__fmul_rn(v[j].z, w), b), 0.0f);
        float x3 = fmaxf(__fadd_rn(__fmul_rn(v[j].w, w), b), 0.0f);
        mx1 = fmaxf(mx1, fmaxf(fmaxf(x0, x1), fmaxf(x2, x3)));
        mxb = fmaxf(mxb, fmaxf(fmaxf(fabsf(v[j].x), fabsf(v[j].y)), fmaxf(fabsf(v[j].z), fabsf(v[j].w))));
    }
    mx1 = blockReduceMax256(mx1);
    __syncthreads();
    mxb = blockReduceMax256(mxb);
    if (threadIdx.x == 0) {
        atomicMax((unsigned*)ws + 0, __float_as_uint(mx1));
        atomicMax((unsigned*)ws + 1, __float_as_uint(mxb));
    }
}

// ---------------- quant1: batch -> bf16-int x1 in [b][hw][c] (LDS transpose) ----------------
__global__ __launch_bounds__(256) void quant1_kernel(const float* __restrict__ batch,
                                                     float* __restrict__ ws) {
    __shared__ unsigned short lds[64 * 260];   // [hw][c], stride 260 ushorts (33.3 KB)
    const float* w1q = ws + OFF_W1Q;
    const float* b1q = ws + OFF_B1Q;
    float s_a1 = __uint_as_float(((unsigned*)ws)[0]) / 127.0f + 1e-8f;
    int b = blockIdx.x / 49, hw0 = (blockIdx.x % 49) * 64;
    int t = threadIdx.x;
    int hw = t & 63, cg = t >> 6;   // cg 0..3
    #pragma unroll
    for (int j = 0; j < 16; j++) {
        int c = cg * 4 + j * 16;
        unsigned short q[4];
        #pragma unroll
        for (int k = 0; k < 4; k++) {
            float w = w1q[c + k], bb = b1q[c + k];
            float x = batch[((size_t)b * 256 + c + k) * 3136 + hw0 + hw];
            float m = clamp8(rintf(fmaxf(__fadd_rn(__fmul_rn(x, w), bb), 0.0f) / s_a1));
            q[k] = bf16u(m);
        }
        *(uint2*)&lds[hw * 260 + c] = *(uint2*)q;
    }
    __syncthreads();
    uint4* outv = (uint4*)((char*)ws + X1B_BYTE);
    #pragma unroll
    for (int j = 0; j < 8; j++) {
        int id = t + j * 256;
        int row = id >> 5, ch = id & 31;
        uint2 lo = *(uint2*)&lds[row * 260 + ch * 8];
        uint2 hi = *(uint2*)&lds[row * 260 + ch * 8 + 4];
        uint4 val; val.x = lo.x; val.y = lo.y; val.z = hi.x; val.w = hi.y;
        outv[(((size_t)b * 3136 + hw0 + row) * 256 + ch * 8) >> 3] = val;
    }
}

// ---------------- prep2 ----------------
__global__ void prep2_kernel(const float* __restrict__ c1w,
                             const float* __restrict__ g2, const float* __restrict__ b2,
                             const float* __restrict__ m2, const float* __restrict__ v2,
                             const float* __restrict__ c2w, float* __restrict__ ws) {
    int bi = blockIdx.x;
    int t = threadIdx.x;
    unsigned short* wq1b = (unsigned short*)(ws + OFF_WQ1B);
    unsigned short* w2b  = (unsigned short*)(ws + OFF_W2B);
    if (bi < BOT) {
        int o = bi;
        float tt = __fmul_rn(g2[o], 1.0f / sqrtf(v2[o] + 1e-5f));
        float wf = __fmul_rn(c1w[o * CIN + t], tt);
        float mx = blockReduceMax256(fabsf(wf));
        float s_w1 = mx / 127.0f + 1e-8f;
        wq1b[o * CIN + t] = bf16u(clamp8(rintf(wf / s_w1)));
        if (t == 0) {
            float s_a1 = __uint_as_float(((unsigned*)ws)[0]) / 127.0f + 1e-8f;
            ws[OFF_SC1 + o] = __fmul_rn(s_a1, s_w1);
            float bf = __fsub_rn(b2[o], __fmul_rn(m2[o], tt));
            float sb = __fmul_rn(s_a1, s_w1);
            ws[OFF_BFQ + o] = __fmul_rn(clampBig(rintf(bf / sb)), sb);
        }
    } else {
        int g = bi - BOT;
        float mx = 0.0f;
        for (int s = t; s < BOT * 9; s += 256) mx = fmaxf(mx, fabsf(c2w[g * BOT * 9 + s]));
        mx = blockReduceMax256(mx);
        float s_w2 = mx / 127.0f + 1e-8f;
        for (int s = t; s < BOT * 9; s += 256) {
            int c = s / 9, tap = s - c * 9;
            w2b[(tap * GRW + g) * BOT + c] = bf16u(clamp8(rintf(c2w[g * BOT * 9 + s] / s_w2)));
        }
        if (t == 0) ws[OFF_SC2 + g] = s_w2;
    }
}

// ---------------- conv1: LDS-free MFMA; A,B fragments straight from global ----------------
// 64 hw x 128 o per block, K=256. 256 thr = 4 waves: mhalf=wv&1 (32 hw), nhalf=wv>>1 (64 o).
__global__ __launch_bounds__(256) void conv1_kernel(float* __restrict__ ws) {
    const unsigned short* x1b  = (const unsigned short*)((char*)ws + X1B_BYTE);
    const unsigned short* wq1b = (const unsigned short*)(ws + OFF_WQ1B);
    const float* sc1 = ws + OFF_SC1;
    const float* bfq = ws + OFF_BFQ;
    float* x2 = (float*)((char*)ws + X2_BYTE);
    int b = blockIdx.x / 49, hw0 = (blockIdx.x % 49) * 64;
    int t = threadIdx.x, lane = t & 63, wv = t >> 6;
    int quad = lane >> 4, l16 = lane & 15;
    int mhalf = wv & 1, nhalf = wv >> 1;
    const unsigned short* arow0 = x1b + ((size_t)b * 3136 + hw0 + mhalf * 32 + l16) * 256 + quad * 8;
    const unsigned short* arow1 = arow0 + 16 * 256;
    const unsigned short* brow  = wq1b + (nhalf * 64 + l16) * 256 + quad * 8;
    f32x4 acc[2][4];
    #pragma unroll
    for (int i = 0; i < 2; i++)
        #pragma unroll
        for (int j = 0; j < 4; j++) acc[i][j] = (f32x4){0.f, 0.f, 0.f, 0.f};
    #pragma unroll
    for (int ks = 0; ks < 8; ks++) {
        bf16x8 a0 = *(const bf16x8*)(arow0 + ks * 32);
        bf16x8 a1 = *(const bf16x8*)(arow1 + ks * 32);
        #pragma unroll
        for (int nt = 0; nt < 4; nt++) {
            bf16x8 bf = *(const bf16x8*)(brow + nt * 16 * 256 + ks * 32);
            acc[0][nt] = __builtin_amdgcn_mfma_f32_16x16x32_bf16(a0, bf, acc[0][nt], 0, 0, 0);
            acc[1][nt] = __builtin_amdgcn_mfma_f32_16x16x32_bf16(a1, bf, acc[1][nt], 0, 0, 0);
        }
    }
    float mx = 0.0f;
    #pragma unroll
    for (int nt = 0; nt < 4; nt++) {
        int o = nhalf * 64 + nt * 16 + l16;
        float s = sc1[o], bb = bfq[o];
        #pragma unroll
        for (int mt = 0; mt < 2; mt++) {
            int hw = hw0 + mhalf * 32 + mt * 16 + quad * 4;
            float4 v;
            v.x = fmaxf(__fadd_rn(__fmul_rn(acc[mt][nt][0], s), bb), 0.0f);
            v.y = fmaxf(__fadd_rn(__fmul_rn(acc[mt][nt][1], s), bb), 0.0f);
            v.z = fmaxf(__fadd_rn(__fmul_rn(acc[mt][nt][2], s), bb), 0.0f);
            v.w = fmaxf(__fadd_rn(__fmul_rn(acc[mt][nt][3], s), bb), 0.0f);
            mx = fmaxf(mx, fmaxf(fmaxf(v.x, v.y), fmaxf(v.z, v.w)));
            *(float4*)&x2[(size_t)(b * BOT + o) * HW + hw] = v;
        }
    }
    mx = waveReduceMax(mx);
    if (lane == 0) atomicMax((unsigned*)ws + 2, __float_as_uint(mx));
}

// ---------------- quant2: x2 fp32 -> bf16-int [b][hw][c] (LDS transpose) ----------------
__global__ __launch_bounds__(256) void quant2_kernel(float* __restrict__ ws) {
    __shared__ unsigned short lds[64 * 132];   // [hw][c], stride 132 (16.9 KB)
    const float* x2 = (const float*)((char*)ws + X2_BYTE);
    float s_a2 = __uint_as_float(((unsigned*)ws)[2]) / 127.0f + 1e-8f;
    int b = blockIdx.x / 49, hw0 = (blockIdx.x % 49) * 64;
    int t = threadIdx.x;
    int hw = t & 63, cg = t >> 6;
    #pragma unroll
    for (int j = 0; j < 8; j++) {
        int c = cg * 4 + j * 16;
        unsigned short q[4];
        #pragma unroll
        for (int k = 0; k < 4; k++) {
            float x = x2[((size_t)b * 128 + c + k) * 3136 + hw0 + hw];
            q[k] = bf16u(clamp8(rintf(x / s_a2)));
        }
        *(uint2*)&lds[hw * 132 + c] = *(uint2*)q;
    }
    __syncthreads();
    uint4* outv = (uint4*)((char*)ws + X2B_BYTE);
    #pragma unroll
    for (int j = 0; j < 4; j++) {
        int id = t + j * 256;
        int row = id >> 4, ch = id & 15;
        uint2 lo = *(uint2*)&lds[row * 132 + ch * 8];
        uint2 hi = *(uint2*)&lds[row * 132 + ch * 8 + 4];
        uint4 val; val.x = lo.x; val.y = lo.y; val.z = hi.x; val.w = hi.y;
        outv[(((size_t)b * 3136 + hw0 + row) * 128 + ch * 8) >> 3] = val;
    }
}

// ---------------- conv2: LDS-free tap-decomposed MFMA ----------------
// block = 128 thr (2 waves), wave = one output row h (56 wide, 4 m-tiles) x 32 g.
__global__ __launch_bounds__(128) void conv2_kernel(float* __restrict__ ws) {
    const unsigned short* x2b = (const unsigned short*)((char*)ws + X2B_BYTE);
    const unsigned short* w2b = (const unsigned short*)(ws + OFF_W2B);
    const float* sc2 = ws + OFF_SC2;
    float* x3 = (float*)((char*)ws + X3_BYTE);
    int b = blockIdx.x / 28;
    int t = threadIdx.x, lane = t & 63;
    int h = (blockIdx.x % 28) * 2 + (t >> 6);
    int quad = lane >> 4, l16 = lane & 15;
    float s_a2 = __uint_as_float(((unsigned*)ws)[2]) / 127.0f + 1e-8f;
    f32x4 acc[4][2];
    #pragma unroll
    for (int i = 0; i < 4; i++) { acc[i][0] = (f32x4){0.f,0.f,0.f,0.f}; acc[i][1] = (f32x4){0.f,0.f,0.f,0.f}; }
    const bf16x8 zero8 = {};
    #pragma unroll
    for (int tap = 0; tap < 9; tap++) {
        int dh = tap / 3, dw = tap % 3;
        int h2 = h + dh - 1;
        if (h2 < 0 || h2 >= 56) continue;
        const unsigned short* abase = x2b + ((size_t)b * 3136 + h2 * 56) * 128 + quad * 8;
        const unsigned short* bbase = w2b + (tap * 32 + l16) * 128 + quad * 8;
        #pragma unroll
        for (int ks = 0; ks < 4; ks++) {
            bf16x8 bv0 = *(const bf16x8*)(bbase + ks * 32);
            bf16x8 bv1 = *(const bf16x8*)(bbase + 16 * 128 + ks * 32);
            #pragma unroll
            for (int mt = 0; mt < 4; mt++) {
                int x = mt * 16 + l16 + dw - 1;
                bf16x8 a = (x >= 0 && x < 56) ? *(const bf16x8*)(abase + (size_t)x * 128 + ks * 32) : zero8;
                acc[mt][0] = __builtin_amdgcn_mfma_f32_16x16x32_bf16(a, bv0, acc[mt][0], 0, 0, 0);
                acc[mt][1] = __builtin_amdgcn_mfma_f32_16x16x32_bf16(a, bv1, acc[mt][1], 0, 0, 0);
            }
        }
    }
    float mx = 0.0f;
    #pragma unroll
    for (int nt = 0; nt < 2; nt++) {
        int g = nt * 16 + l16;
        float s2 = __fmul_rn(s_a2, sc2[g]);
        #pragma unroll
        for (int mt = 0; mt < 4; mt++) {
            int x = mt * 16 + quad * 4;
            if (x < 56) {
                float4 v;
                v.x = __fmul_rn(acc[mt][nt][0], s2);
                v.y = __fmul_rn(acc[mt][nt][1], s2);
                v.z = __fmul_rn(acc[mt][nt][2], s2);
                v.w = __fmul_rn(acc[mt][nt][3], s2);
                mx = fmaxf(mx, fmaxf(fmaxf(fabsf(v.x), fabsf(v.y)), fmaxf(fabsf(v.z), fabsf(v.w))));
                *(float4*)&x3[(size_t)(b * GRW + g) * HW + h * 56 + x] = v;
            }
        }
    }
    mx = waveReduceMax(mx);
    if (lane == 0) atomicMax((unsigned*)ws + 3, __float_as_uint(mx));
}

// ---------------- output: concat + fake-quant, 8-deep MLP ----------------
__global__ __launch_bounds__(256) void outq_kernel(const float4* __restrict__ batch4,
                                                   const float* __restrict__ ws,
                                                   float* __restrict__ out) {
    const float4* x34 = (const float4*)((const char*)ws + X3_BYTE);
    float maxb = __uint_as_float(((const unsigned*)ws)[1]);
    float max3 = __uint_as_float(((const unsigned*)ws)[3]);
    float s_out = fmaxf(maxb, max3) / 127.0f + 1e-8f;
    float4* out4 = (float4*)out;
    int base = blockIdx.x * 2048 + threadIdx.x;   // grid 3528: 3528*2048 = NOUT/4 exactly
    float4 v[8];
    #pragma unroll
    for (int j = 0; j < 8; j++) {
        int i = base + j * 256;
        int chl = i / 784;
        int b = chl / COUT;
        int ch = chl - b * COUT;
        int hw4 = i - chl * 784;
        v[j] = (ch < CIN) ? batch4[(b * CIN + ch) * 784 + hw4]
                          : x34[(b * GRW + (ch - CIN)) * 784 + hw4];
    }
    #pragma unroll
    for (int j = 0; j < 8; j++) {
        float4 r;
        r.x = __fmul_rn(clamp8(rintf(v[j].x / s_out)), s_out);
        r.y = __fmul_rn(clamp8(rintf(v[j].y / s_out)), s_out);
        r.z = __fmul_rn(clamp8(rintf(v[j].z / s_out)), s_out);
        r.w = __fmul_rn(clamp8(rintf(v[j].w / s_out)), s_out);
        out4[base + j * 256] = r;
    }
    if (blockIdx.x == 0 && threadIdx.x == 0) out[NOUT] = s_out;
}

extern "C" void kernel_launch(void* const* d_in, const int* in_sizes, int n_in,
                              void* d_out, int out_size, void* d_ws, size_t ws_size,
                              hipStream_t stream) {
    const float* batch = (const float*)d_in[0];
    const float* s_in  = (const float*)d_in[1];
    const float* g1    = (const float*)d_in[2];
    const float* b1    = (const float*)d_in[3];
    const float* m1    = (const float*)d_in[4];
    const float* v1    = (const float*)d_in[5];
    const float* c1w   = (const float*)d_in[6];
    const float* g2    = (const float*)d_in[7];
    const float* b2    = (const float*)d_in[8];
    const float* m2    = (const float*)d_in[9];
    const float* v2    = (const float*)d_in[10];
    const float* c2w   = (const float*)d_in[11];
    float* out = (float*)d_out;
    float* ws  = (float*)d_ws;

    hipLaunchKernelGGL(prep1_kernel, dim3(1), dim3(256), 0, stream, g1, b1, m1, v1, s_in, ws);
    hipLaunchKernelGGL(max1_kernel, dim3(3136), dim3(256), 0, stream, (const float4*)batch, ws);
    hipLaunchKernelGGL(quant1_kernel, dim3(32 * 49), dim3(256), 0, stream, batch, ws);
    hipLaunchKernelGGL(prep2_kernel, dim3(160), dim3(256), 0, stream, c1w, g2, b2, m2, v2, c2w, ws);
    hipLaunchKernelGGL(conv1_kernel, dim3(32 * 49), dim3(256), 0, stream, ws);
    hipLaunchKernelGGL(quant2_kernel, dim3(32 * 49), dim3(256), 0, stream, ws);
    hipLaunchKernelGGL(conv2_kernel, dim3(32 * 28), dim3(128), 0, stream, ws);
    hipLaunchKernelGGL(outq_kernel, dim3(3528), dim3(256), 0, stream, (const float4*)batch, ws, out);
}